// Round 8
// baseline (216.884 us; speedup 1.0000x reference)
//
#include <hip/hip_runtime.h>
#include <hip/hip_bf16.h>

// GraphConvNet: x:[8,2048,32] f32, A0/A1/A2:[8,2048,2048] f32 row-normalized,
// W:[64,224], b/gamma/beta:[64].
// nconv: out[n,w,l] = sum_v A[n,v,w] * x[n,v,l]
// feat = concat([x, x1_0, x2_0, x1_1, x2_1, x1_2, x2_2])  (224 ch)
// h = feat @ W^T + b ; BN over (n,v) per channel; out f32 [8,2048,64]
//
// DRAM-page-locality design: block = (n, 256-col w-strip, K-eighth).
// A staged via global_load_lds in 1 KB contiguous row segments (vs 128 B
// before) -> DRAM page hits. K-split across blocks -> 8 partials + reduce.

#define V    2048
#define NB   8
#define CIN  32
#define COUT 64
#define CTOT 224

typedef __attribute__((ext_vector_type(8))) short bf16x8;
typedef __attribute__((ext_vector_type(16))) float f32x16;

static __device__ __forceinline__ short f2bf(float f) {
  __hip_bfloat16 h = __float2bfloat16(f);  // RNE
  return *reinterpret_cast<short*>(&h);
}

static __device__ __forceinline__ void gll16(const float* g, float* l) {
  // async global->LDS, 16B/lane; LDS dst = wave-uniform base + lane*16
  __builtin_amdgcn_global_load_lds(
      (const __attribute__((address_space(1))) void*)g,
      (__attribute__((address_space(3))) void*)l, 16, 0, 0);
}

// ---------------------------------------------------------------------------
// nconv partial: block (n, s=256-col strip, kq=K-eighth of 256 v), 4 waves.
// Per chunk (16 v): A tile 16x256 f32 (16 KB) staged cooperatively, one
// gll16 = one full 1 KB row (lane 16B slices); wave q stages rows 4q..4q+3.
// X[16x32] per-wave in regs (8 dwords). 12 VMEM/wave/chunk uniform.
// Ring 4, stage-ahead 2, vmcnt(24) + raw s_barrier per chunk (loads stay in
// flight across barriers; restaged slot was last read 2 barriers ago).
// Wave q owns cols [64q,64q+64): 2 MFMAs/chunk. k-map v=16c+8g+j (same
// bijection both operands). Output: K-partial to Ppart[kq], reduced later.
// ---------------------------------------------------------------------------
__global__ __launch_bounds__(256, 2) void nconv_mfma_kernel(
    const float* __restrict__ Adj, const float* __restrict__ Xin,
    float* __restrict__ Ppart) {
  __shared__ float SA[4][16][256];  // 64 KB ring -> 2 blocks/CU

  const int bid  = blockIdx.x;     // 512 blocks
  const int n    = bid >> 6;
  const int s    = (bid >> 3) & 7; // 256-col strip
  const int kq   = bid & 7;        // K-eighth
  const int t    = threadIdx.x;
  const int q    = t >> 6;         // wave id: col-quarter + staging rows
  const int lane = t & 63;
  const int g    = lane >> 5;
  const int mn   = lane & 31;

  const float* __restrict__ Ab =
      Adj + (size_t)n * V * V + (size_t)(kq * 256) * V + s * 256;
  const float* __restrict__ Xp =
      Xin + ((size_t)n * V + kq * 256) * CIN + mn;

  float xr0[8], xr1[8], xr2[8], xr3[8];
  f32x16 acc0, acc1;
#pragma unroll
  for (int r = 0; r < 16; ++r) { acc0[r] = 0.f; acc1[r] = 0.f; }

#define STG(SL, C)                                                        \
  do {                                                                    \
    _Pragma("unroll") for (int rr = 0; rr < 4; ++rr)                      \
      gll16(Ab + (size_t)((C) * 16 + 4 * q + rr) * V + lane * 4,          \
            &SA[SL][4 * q + rr][0]);                                      \
    _Pragma("unroll") for (int j = 0; j < 8; ++j)                         \
      xr##SL[j] = Xp[((C) * 16 + 8 * g + j) * CIN];                       \
    __builtin_amdgcn_sched_barrier(0);                                    \
  } while (0)

#define WAITB(N)                                                          \
  do {                                                                    \
    asm volatile("s_waitcnt vmcnt(" #N ")" ::: "memory");                 \
    __builtin_amdgcn_s_barrier();                                         \
    __builtin_amdgcn_sched_barrier(0);                                    \
  } while (0)

#define CMP(SL)                                                           \
  do {                                                                    \
    float b0f[8], b1f[8];                                                 \
    _Pragma("unroll") for (int j = 0; j < 8; ++j) {                       \
      b0f[j] = SA[SL][8 * g + j][64 * q + mn];                            \
      b1f[j] = SA[SL][8 * g + j][64 * q + 32 + mn];                       \
    }                                                                     \
    bf16x8 aop_, b0_, b1_;                                                \
    _Pragma("unroll") for (int j = 0; j < 8; ++j) {                       \
      aop_[j] = f2bf(xr##SL[j]);                                          \
      b0_[j] = f2bf(b0f[j]);                                              \
      b1_[j] = f2bf(b1f[j]);                                              \
    }                                                                     \
    acc0 = __builtin_amdgcn_mfma_f32_32x32x16_bf16(aop_, b0_, acc0, 0, 0, 0); \
    acc1 = __builtin_amdgcn_mfma_f32_32x32x16_bf16(aop_, b1_, acc1, 0, 0, 0); \
  } while (0)

  // prologue: 2 chunks ahead (24 VMEM outstanding)
  STG(0, 0);
  STG(1, 1);
#pragma unroll 1
  for (int i = 0; i < 3; ++i) {  // chunks c=4i..4i+3, stages c+2..c+5
    const int c = 4 * i;
    STG(2, c + 2); WAITB(24); CMP(0);
    STG(3, c + 3); WAITB(24); CMP(1);
    STG(0, c + 4); WAITB(24); CMP(2);
    STG(1, c + 5); WAITB(24); CMP(3);
  }
  STG(2, 14); WAITB(24); CMP(0);  // chunk 12
  STG(3, 15); WAITB(24); CMP(1);  // chunk 13
  WAITB(12); CMP(2);              // chunk 14
  WAITB(0);  CMP(3);              // chunk 15

#undef STG
#undef WAITB
#undef CMP

  // ---- store K-partial (each wave owns full K-eighth of its 64 cols) ----
  float* __restrict__ Pp =
      Ppart + (size_t)(kq * NB + n) * V * CIN;
  const int w0 = s * 256 + 64 * q;
#pragma unroll
  for (int u = 0; u < 4; ++u) {
    const int l = 8 * u + 4 * g;  // l = (r&3)+8*(r>>2)+4g, r=4u..4u+3
    *(float4*)(Pp + (size_t)(w0 + mn) * CIN + l) =
        make_float4(acc0[4 * u], acc0[4 * u + 1], acc0[4 * u + 2],
                    acc0[4 * u + 3]);
    *(float4*)(Pp + (size_t)(w0 + 32 + mn) * CIN + l) =
        make_float4(acc1[4 * u], acc1[4 * u + 1], acc1[4 * u + 2],
                    acc1[4 * u + 3]);
  }
}

// ---------------------------------------------------------------------------
// K-partial reduce: x = sum over 8 kq partials (deterministic, no atomics).
// ---------------------------------------------------------------------------
__global__ __launch_bounds__(256) void kred_kernel(
    const float* __restrict__ P, float* __restrict__ Xout) {
  const size_t i4 = (size_t)blockIdx.x * 256 + threadIdx.x;  // 131072 f4
  const size_t S4 = (size_t)NB * V * CIN / 4;
  const float4* p = (const float4*)P + i4;
  float4 a = p[0];
#pragma unroll
  for (int k = 1; k < 8; ++k) {
    float4 b = p[(size_t)k * S4];
    a.x += b.x; a.y += b.y; a.z += b.z; a.w += b.w;
  }
  ((float4*)Xout)[i4] = a;
}

// ---------------------------------------------------------------------------
// conv 1x1 + bias + BN batch-stats partials (unchanged, passing).
// ---------------------------------------------------------------------------
__global__ __launch_bounds__(256) void conv_bn_stats_kernel(
    const float* __restrict__ W, const float* __restrict__ bias,
    const float* __restrict__ p0, const float* __restrict__ p1,
    const float* __restrict__ p2, const float* __restrict__ p3,
    const float* __restrict__ p4, const float* __restrict__ p5,
    const float* __restrict__ p6, float* __restrict__ hout,
    float* __restrict__ stats) {
  __shared__ float Wl[COUT * CTOT];
  __shared__ float Fl[64 * CTOT];
  const int t = threadIdx.x;
  const int R0 = blockIdx.x * 64;

#pragma unroll
  for (int s = 0; s < 14; ++s) {
    int fl = t + s * 256;
    int o = fl / 56, c4 = fl % 56;
    float4 wv = *(const float4*)(W + o * CTOT + c4 * 4);
    int c = c4 * 4;
    int csw = c ^ (((o >> 2) & 7) << 2);
    *(float4*)&Wl[o * CTOT + csw] = wv;
  }
  const float* parts[7] = {p0, p1, p2, p3, p4, p5, p6};
#pragma unroll
  for (int p = 0; p < 7; ++p) {
    const float* __restrict__ src = parts[p] + (size_t)R0 * CIN;
#pragma unroll
    for (int s = 0; s < 2; ++s) {
      int fl = t + s * 256;
      int r = fl >> 3, c4 = fl & 7;
      float4 v = *(const float4*)(src + r * CIN + c4 * 4);
      int c = p * 32 + c4 * 4;
      int csw = c ^ (((r >> 2) & 7) << 2);
      *(float4*)&Fl[r * CTOT + csw] = v;
    }
  }
  __syncthreads();

  const int rg = t & 15, og = t >> 4;
  const int r0 = rg * 4, o0 = og * 4;
  float acc[4][4];
#pragma unroll
  for (int i = 0; i < 4; ++i)
#pragma unroll
    for (int j = 0; j < 4; ++j) acc[i][j] = bias[o0 + j];

  const int fsw = (rg & 7) << 2;
  const int wsw = (og & 7) << 2;
  for (int cc = 0; cc < CTOT; cc += 4) {
    float4 f[4], w[4];
#pragma unroll
    for (int i = 0; i < 4; ++i)
      f[i] = *(const float4*)&Fl[(r0 + i) * CTOT + (cc ^ fsw)];
#pragma unroll
    for (int j = 0; j < 4; ++j)
      w[j] = *(const float4*)&Wl[(o0 + j) * CTOT + (cc ^ wsw)];
#pragma unroll
    for (int i = 0; i < 4; ++i)
#pragma unroll
      for (int j = 0; j < 4; ++j)
        acc[i][j] += f[i].x * w[j].x + f[i].y * w[j].y + f[i].z * w[j].z +
                     f[i].w * w[j].w;
  }

#pragma unroll
  for (int i = 0; i < 4; ++i) {
    *(float4*)(hout + (size_t)(R0 + r0 + i) * COUT + o0) =
        make_float4(acc[i][0], acc[i][1], acc[i][2], acc[i][3]);
  }

  __syncthreads();
  float* red = Fl;
#pragma unroll
  for (int j = 0; j < 4; ++j) {
    float s = acc[0][j] + acc[1][j] + acc[2][j] + acc[3][j];
    float qq = acc[0][j] * acc[0][j] + acc[1][j] * acc[1][j] +
               acc[2][j] * acc[2][j] + acc[3][j] * acc[3][j];
    red[(o0 + j) * 16 + rg] = s;
    red[1024 + (o0 + j) * 16 + rg] = qq;
  }
  __syncthreads();
  if (t < 128) {
    int o = t & 63, which = t >> 6;
    const float* b = red + which * 1024 + o * 16;
    float v = 0.f;
#pragma unroll
    for (int k = 0; k < 16; ++k) v += b[k];
    atomicAdd(stats + which * COUT + o, v);
  }
}

// ---------------------------------------------------------------------------
__global__ __launch_bounds__(256) void bn_apply_kernel(
    float* __restrict__ hout, const float* __restrict__ stats,
    const float* __restrict__ gamma, const float* __restrict__ beta) {
  const int i4 = blockIdx.x * 256 + threadIdx.x;
  const int oi = i4 & 15;
  float4 h = ((const float4*)hout)[i4];
  const float4 s = ((const float4*)stats)[oi];
  const float4 q = ((const float4*)(stats + COUT))[oi];
  const float4 g = ((const float4*)gamma)[oi];
  const float4 bb = ((const float4*)beta)[oi];
  const float inv = 1.f / 16384.f;
  float m, vv, rs;
  m = s.x * inv; vv = q.x * inv - m * m; rs = rsqrtf(vv + 1e-5f);
  h.x = (h.x - m) * rs * g.x + bb.x;
  m = s.y * inv; vv = q.y * inv - m * m; rs = rsqrtf(vv + 1e-5f);
  h.y = (h.y - m) * rs * g.y + bb.y;
  m = s.z * inv; vv = q.z * inv - m * m; rs = rsqrtf(vv + 1e-5f);
  h.z = (h.z - m) * rs * g.z + bb.z;
  m = s.w * inv; vv = q.w * inv - m * m; rs = rsqrtf(vv + 1e-5f);
  h.w = (h.w - m) * rs * g.w + bb.w;
  ((float4*)hout)[i4] = h;
}

// ---------------------------------------------------------------------------
extern "C" void kernel_launch(void* const* d_in, const int* in_sizes, int n_in,
                              void* d_out, int out_size, void* d_ws,
                              size_t ws_size, hipStream_t stream) {
  const float* x     = (const float*)d_in[0];
  const float* A0    = (const float*)d_in[1];
  const float* A1    = (const float*)d_in[2];
  const float* A2    = (const float*)d_in[3];
  const float* W     = (const float*)d_in[4];
  const float* b     = (const float*)d_in[5];
  const float* gamma = (const float*)d_in[6];
  const float* beta  = (const float*)d_in[7];
  float* out = (float*)d_out;

  char* ws = (char*)d_ws;
  float* stats = (float*)ws;
  const size_t BUF = (size_t)NB * V * CIN;  // 524288 floats (2 MB)
  float* x1_0 = (float*)(ws + 4096);
  float* x2_0 = x1_0 + BUF;
  float* x1_1 = x2_0 + BUF;
  float* x2_1 = x1_1 + BUF;
  float* x1_2 = x2_1 + BUF;
  float* x2_2 = x1_2 + BUF;
  float* P    = x2_2 + BUF;                 // 8 partials x 2 MB = 16.8 MB

  hipMemsetAsync(stats, 0, 2 * COUT * sizeof(float), stream);

  dim3 blk(256);
  // per-A pairs so hop2 re-reads A from Infinity Cache
  nconv_mfma_kernel<<<dim3(512), blk, 0, stream>>>(A0, x, P);
  kred_kernel<<<dim3(512), blk, 0, stream>>>(P, x1_0);
  nconv_mfma_kernel<<<dim3(512), blk, 0, stream>>>(A0, x1_0, P);
  kred_kernel<<<dim3(512), blk, 0, stream>>>(P, x2_0);

  nconv_mfma_kernel<<<dim3(512), blk, 0, stream>>>(A1, x, P);
  kred_kernel<<<dim3(512), blk, 0, stream>>>(P, x1_1);
  nconv_mfma_kernel<<<dim3(512), blk, 0, stream>>>(A1, x1_1, P);
  kred_kernel<<<dim3(512), blk, 0, stream>>>(P, x2_1);

  nconv_mfma_kernel<<<dim3(512), blk, 0, stream>>>(A2, x, P);
  kred_kernel<<<dim3(512), blk, 0, stream>>>(P, x1_2);
  nconv_mfma_kernel<<<dim3(512), blk, 0, stream>>>(A2, x1_2, P);
  kred_kernel<<<dim3(512), blk, 0, stream>>>(P, x2_2);

  conv_bn_stats_kernel<<<dim3(256), blk, 0, stream>>>(
      W, b, x, x1_0, x2_0, x1_1, x2_1, x1_2, x2_2, out, stats);
  bn_apply_kernel<<<dim3(1024), blk, 0, stream>>>(out, stats, gamma, beta);
}